// Round 2
// baseline (16001.913 us; speedup 1.0000x reference)
//
#include <hip/hip_runtime.h>
#include <cstdint>
#include <cstddef>

typedef __bf16 bf16;
typedef __bf16 bf16x8 __attribute__((ext_vector_type(8)));
typedef float  f32x4  __attribute__((ext_vector_type(4)));

#define T_SEQ 512
#define NB    256
#define IND   128
#define NH    256
#define NL    6
#define NG    768   // 3*NH

// ---------------- fp32 -> bf16 conversion ----------------
__global__ void cvt_kernel(const float* __restrict__ src, bf16* __restrict__ dst, int n4) {
    int i = blockIdx.x * blockDim.x + threadIdx.x;
    if (i < n4) {
        float4 v = reinterpret_cast<const float4*>(src)[i];
        bf16 o0 = (bf16)v.x, o1 = (bf16)v.y, o2 = (bf16)v.z, o3 = (bf16)v.w;
        ushort4 pk;
        pk.x = *(unsigned short*)&o0; pk.y = *(unsigned short*)&o1;
        pk.z = *(unsigned short*)&o2; pk.w = *(unsigned short*)&o3;
        reinterpret_cast<ushort4*>(dst)[i] = pk;
    }
}

// bc[l][j] = b_ih[l][j] + (j<512 ? b_hh[l][j] : 0)   (fold r,z hidden-bias into gi)
__global__ void bias_combine(const float* __restrict__ bih, const float* __restrict__ bhh,
                             float* __restrict__ bc, int n) {
    int i = blockIdx.x * blockDim.x + threadIdx.x;
    if (i < n) {
        int j = i % NG;
        bc[i] = bih[i] + (j < 512 ? bhh[i] : 0.f);
    }
}

// ---------------- input GEMM: C[m,n] = sum_k A[m,k]*W[n,k] + bias[n] ----------------
// A: (M, K) row-major (fp32 if F32IN else bf16); W: (768, K) bf16 row-major.
// 128x128 tile, BK=32, 4 waves (2x2), each wave 64x64 = 4x4 MFMA tiles.
template<int KT, bool F32IN>
__global__ __launch_bounds__(256) void gi_gemm(const void* __restrict__ Av,
                                               const bf16* __restrict__ W,
                                               const float* __restrict__ bias,
                                               float* __restrict__ C) {
    constexpr int K = KT * 32;
    __shared__ bf16 sA[128 * 32];
    __shared__ bf16 sB[128 * 32];
    const int tid = threadIdx.x;
    const int wid = tid >> 6, l = tid & 63;
    const int lr = l & 15, lg = l >> 4;
    const int m0 = blockIdx.x * 128, n0 = blockIdx.y * 128;
    const int wm = (wid & 1) * 64, wn = (wid >> 1) * 64;
    const int srow = tid >> 2, skoff = (tid & 3) * 8;
    const bf16* pB = W + (size_t)(n0 + srow) * K + skoff;

    f32x4 acc[4][4] = {};
    for (int kt = 0; kt < KT; ++kt) {
        bf16x8 ta0, ta1;
        if (F32IN) {
            const float* pA = (const float*)Av + (size_t)(m0 + srow) * K + kt * 32 + skoff;
            float4 v0 = *(const float4*)pA;
            float4 v1 = *(const float4*)(pA + 4);
            ta0 = bf16x8{(bf16)v0.x,(bf16)v0.y,(bf16)v0.z,(bf16)v0.w,
                         (bf16)v1.x,(bf16)v1.y,(bf16)v1.z,(bf16)v1.w};
            const float* pA1 = pA + (size_t)64 * K;
            float4 u0 = *(const float4*)pA1;
            float4 u1 = *(const float4*)(pA1 + 4);
            ta1 = bf16x8{(bf16)u0.x,(bf16)u0.y,(bf16)u0.z,(bf16)u0.w,
                         (bf16)u1.x,(bf16)u1.y,(bf16)u1.z,(bf16)u1.w};
        } else {
            const bf16* pA = (const bf16*)Av + (size_t)(m0 + srow) * K + kt * 32 + skoff;
            ta0 = *(const bf16x8*)pA;
            ta1 = *(const bf16x8*)(pA + (size_t)64 * K);
        }
        bf16x8 tb0 = *(const bf16x8*)(pB + kt * 32);
        bf16x8 tb1 = *(const bf16x8*)(pB + (size_t)64 * K + kt * 32);
        __syncthreads();
        *(bf16x8*)((char*)sA + tid * 16)        = ta0;
        *(bf16x8*)((char*)sA + 4096 + tid * 16) = ta1;
        *(bf16x8*)((char*)sB + tid * 16)        = tb0;
        *(bf16x8*)((char*)sB + 4096 + tid * 16) = tb1;
        __syncthreads();
        bf16x8 av[4], bv[4];
#pragma unroll
        for (int i = 0; i < 4; ++i)
            av[i] = *(const bf16x8*)((char*)sA + (wm + i * 16 + lr) * 64 + lg * 16);
#pragma unroll
        for (int j = 0; j < 4; ++j)
            bv[j] = *(const bf16x8*)((char*)sB + (wn + j * 16 + lr) * 64 + lg * 16);
#pragma unroll
        for (int i = 0; i < 4; ++i)
#pragma unroll
            for (int j = 0; j < 4; ++j)
                acc[i][j] = __builtin_amdgcn_mfma_f32_16x16x32_bf16(av[i], bv[j], acc[i][j], 0, 0, 0);
    }
    // epilogue: per tile, C row = lg*4+q (M), col = lr (N)
#pragma unroll
    for (int j = 0; j < 4; ++j) {
        int col = n0 + wn + j * 16 + lr;
        float bj = bias[col];
#pragma unroll
        for (int i = 0; i < 4; ++i) {
            size_t mrow = (size_t)m0 + wm + i * 16 + lg * 4;
            float* cp = C + mrow * NG + col;
#pragma unroll
            for (int q = 0; q < 4; ++q)
                cp[(size_t)q * NG] = acc[i][j][q] + bj;
        }
    }
}

// ---------------- recurrent scan, W_hh resident in VGPRs ----------------
__device__ __forceinline__ float sigm(float x) {
    return __builtin_amdgcn_rcpf(1.f + __expf(-x));
}
__device__ __forceinline__ float tanh_f(float x) {
    return __builtin_amdgcn_rcpf(1.f + __expf(-2.f * x)) * 2.f - 1.f;
}

// 16 blocks x 512 threads (8 waves). Block owns batch rows [b0, b0+16).
// Wave w owns H-columns [32w, 32w+32) of all 3 gates:
//   48 B-fragments (bf16x8) = 192 VGPRs/lane -> whole W_hh (384 KB bf16) in CU registers.
// h: bf16 copy in LDS (A-fragment source, stride 264 bf16), fp32 master in registers.
// Processes nt steps of a T-chunk; carries h via hstate between chunk launches.
template<int LAST>
__global__ __launch_bounds__(512, 2) void gru_recur(
        const float* __restrict__ gi,      // (nt, NB, NG) chunk
        const bf16* __restrict__ Whh,
        const float* __restrict__ bhn_p,   // b_hh[l] + 512 (n-gate hidden bias)
        const float* __restrict__ hinit,   // h0 slice (chunk 0) or hstate
        float* __restrict__ hstate,
        bf16* __restrict__ ybf,            // full-tensor bf16 out (if !LAST)
        float* __restrict__ yf,            // d_out fp32 (if LAST)
        int t0, int nt) {
    __shared__ bf16 hs[16][264];
    const int tid = threadIdx.x;
    const int w = tid >> 6, l = tid & 63;
    const int lr = l & 15, lg = l >> 4;
    const int b0 = blockIdx.x * 16;
    const int jw = w * 32;

    // W_hh B-fragments: B[k][n] = Whh[n][k], n = g*256 + jw + jt*16 + lr
    bf16x8 wf[3][2][8];
#pragma unroll
    for (int g = 0; g < 3; ++g)
#pragma unroll
        for (int jt = 0; jt < 2; ++jt) {
            const bf16* wp = Whh + (size_t)(g * 256 + jw + jt * 16 + lr) * NH + lg * 8;
#pragma unroll
            for (int kt = 0; kt < 8; ++kt)
                wf[g][jt][kt] = *(const bf16x8*)(wp + kt * 32);
        }

    float bhn[2];
#pragma unroll
    for (int jt = 0; jt < 2; ++jt)
        bhn[jt] = bhn_p[jw + jt * 16 + lr];

    float hreg[2][4];
#pragma unroll
    for (int jt = 0; jt < 2; ++jt)
#pragma unroll
        for (int q = 0; q < 4; ++q) {
            int row = lg * 4 + q, col = jw + jt * 16 + lr;
            float h = hinit[(size_t)(b0 + row) * NH + col];
            hreg[jt][q] = h;
            hs[row][col] = (bf16)h;
        }
    __syncthreads();

    for (int t = 0; t < nt; ++t) {
        // prefetch gi for this step (independent of h -> overlaps MFMA)
        const size_t gbase = ((size_t)t * NB + b0) * NG;
        float ir[2][4], iz[2][4], inn[2][4];
#pragma unroll
        for (int jt = 0; jt < 2; ++jt)
#pragma unroll
            for (int q = 0; q < 4; ++q) {
                int row = lg * 4 + q, col = jw + jt * 16 + lr;
                const float* p = gi + gbase + (size_t)row * NG + col;
                ir[jt][q]  = p[0];
                iz[jt][q]  = p[256];
                inn[jt][q] = p[512];
            }
        // gh = h @ Whh^T for this wave's 96 gate-columns
        f32x4 acc[3][2] = {};
#pragma unroll
        for (int kt = 0; kt < 8; ++kt) {
            bf16x8 a = *(const bf16x8*)((const char*)hs + lr * 528 + kt * 64 + lg * 16);
#pragma unroll
            for (int g = 0; g < 3; ++g)
#pragma unroll
                for (int jt = 0; jt < 2; ++jt)
                    acc[g][jt] = __builtin_amdgcn_mfma_f32_16x16x32_bf16(a, wf[g][jt][kt], acc[g][jt], 0, 0, 0);
        }
        __syncthreads();   // all waves done reading hs before rewrite
#pragma unroll
        for (int jt = 0; jt < 2; ++jt)
#pragma unroll
            for (int q = 0; q < 4; ++q) {
                int row = lg * 4 + q, col = jw + jt * 16 + lr;
                float r = sigm(ir[jt][q] + acc[0][jt][q]);        // b_hh_r folded into gi
                float z = sigm(iz[jt][q] + acc[1][jt][q]);        // b_hh_z folded into gi
                float n = tanh_f(inn[jt][q] + r * (acc[2][jt][q] + bhn[jt]));
                float h = hreg[jt][q];
                float hn = n + z * (h - n);
                hreg[jt][q] = hn;
                hs[row][col] = (bf16)hn;
                size_t oidx = ((size_t)(t0 + t) * NB + b0 + row) * NH + col;
                if (LAST) yf[oidx] = hn;
                else      ybf[oidx] = (bf16)hn;
            }
        __syncthreads();   // hs writes visible before next step's reads
    }
    // persist h for next chunk
#pragma unroll
    for (int jt = 0; jt < 2; ++jt)
#pragma unroll
        for (int q = 0; q < 4; ++q) {
            int row = lg * 4 + q, col = jw + jt * 16 + lr;
            hstate[(size_t)(b0 + row) * NH + col] = hreg[jt][q];
        }
}

// ---------------- launcher ----------------
extern "C" void kernel_launch(void* const* d_in, const int* in_sizes, int n_in,
                              void* d_out, int out_size, void* d_ws, size_t ws_size,
                              hipStream_t stream) {
    const float* x    = (const float*)d_in[0];
    const float* h0   = (const float*)d_in[1];
    const float* wih0 = (const float*)d_in[2];
    const float* wihr = (const float*)d_in[3];
    const float* whh  = (const float*)d_in[4];
    const float* bih  = (const float*)d_in[5];
    const float* bhh  = (const float*)d_in[6];

    // fixed ws carve (bytes): total 4,802,560
    char* wsp = (char*)d_ws;
    bf16*  wbih0  = (bf16*)(wsp + 0);          // 768*128*2      = 196,608
    bf16*  wbihr  = (bf16*)(wsp + 196608);     // 5*768*256*2    = 1,966,080
    bf16*  wbhh   = (bf16*)(wsp + 2162688);    // 6*768*256*2    = 2,359,296
    float* bc     = (float*)(wsp + 4521984);   // 6*768*4        = 18,432
    float* hstate = (float*)(wsp + 4540416);   // 256*256*4      = 262,144
    float* gi     = (float*)(wsp + 4802560);   // Tc*256*768*4 per chunk

    const size_t FIXED = 4802560;
    const size_t CHUNK1 = (size_t)NB * NG * 4; // 786,432 B per timestep
    size_t avail = ws_size > FIXED ? ws_size - FIXED : 0;
    int Tc = T_SEQ;
    while (Tc > 1 && (size_t)Tc * CHUNK1 > avail) Tc >>= 1;
    if ((size_t)Tc * CHUNK1 > avail) return;   // ws hopelessly small (<5.6 MB)
    const int nc = T_SEQ / Tc;

    // one-time (per-call) weight/bias prep
    cvt_kernel<<<96,   256, 0, stream>>>(wih0, wbih0, 98304 / 4);
    cvt_kernel<<<960,  256, 0, stream>>>(wihr, wbihr, 983040 / 4);
    cvt_kernel<<<1152, 256, 0, stream>>>(whh,  wbhh,  1179648 / 4);
    bias_combine<<<18, 256, 0, stream>>>(bih, bhh, bc, NL * NG);

    // y ping-pong lives inside d_out: lower/upper 64 MB bf16 halves.
    // even layer -> upper half (so y4 is upper; fp32 final writes never clobber
    // unread y4 rows: (c+1)*Tc*262144 <= 64MB + (c+1)*Tc*131072 for (c+1)Tc<=512).
    bf16* yhalf0 = (bf16*)d_out;
    bf16* yhalf1 = (bf16*)((char*)d_out + 67108864);

    const void* gin = x;
    bool ginF32 = true;
    for (int lyr = 0; lyr < NL; ++lyr) {
        const bf16* wih = (lyr == 0) ? wbih0 : wbihr + (size_t)(lyr - 1) * NG * NH;
        bf16* yout = (lyr % 2 == 0) ? yhalf1 : yhalf0;
        const bf16* whh_l = wbhh + (size_t)lyr * NG * NH;
        const float* bhn_l = bhh + (size_t)lyr * NG + 512;

        for (int c = 0; c < nc; ++c) {
            dim3 gg(Tc * 2, NG / 128);   // (Tc*256/128, 6)
            if (ginF32) {
                const void* Ap = (const void*)((const float*)gin + (size_t)c * Tc * NB * IND);
                gi_gemm<4, true><<<gg, 256, 0, stream>>>(Ap, wih, bc + lyr * NG, gi);
            } else {
                const void* Ap = (const void*)((const bf16*)gin + (size_t)c * Tc * NB * NH);
                gi_gemm<8, false><<<gg, 256, 0, stream>>>(Ap, wih, bc + lyr * NG, gi);
            }
            const float* hin = (c == 0) ? h0 + (size_t)lyr * NB * NH : hstate;
            if (lyr == NL - 1)
                gru_recur<1><<<16, 512, 0, stream>>>(gi, whh_l, bhn_l, hin, hstate,
                                                     (bf16*)nullptr, (float*)d_out,
                                                     c * Tc, Tc);
            else
                gru_recur<0><<<16, 512, 0, stream>>>(gi, whh_l, bhn_l, hin, hstate,
                                                     yout, (float*)nullptr,
                                                     c * Tc, Tc);
        }
        gin = yout;
        ginF32 = false;
    }
}

// Round 9
// 8020.493 us; speedup vs baseline: 1.9951x; 1.9951x over previous
//
#include <hip/hip_runtime.h>
#include <cstdint>
#include <cstddef>

typedef __bf16 bf16;
typedef __bf16 bf16x8 __attribute__((ext_vector_type(8)));
typedef float  f32x4  __attribute__((ext_vector_type(4)));

#define T_SEQ 512
#define NB    256
#define IND   128
#define NH    256
#define NL    6
#define NG    768   // 3*NH

__device__ __forceinline__ float bf2f(unsigned short u) {
    return __uint_as_float((unsigned int)u << 16);
}

// ---------------- fp32 -> bf16 conversion ----------------
__global__ void cvt_kernel(const float* __restrict__ src, bf16* __restrict__ dst, int n4) {
    int i = blockIdx.x * blockDim.x + threadIdx.x;
    if (i < n4) {
        float4 v = reinterpret_cast<const float4*>(src)[i];
        bf16 o0 = (bf16)v.x, o1 = (bf16)v.y, o2 = (bf16)v.z, o3 = (bf16)v.w;
        ushort4 pk;
        pk.x = *(unsigned short*)&o0; pk.y = *(unsigned short*)&o1;
        pk.z = *(unsigned short*)&o2; pk.w = *(unsigned short*)&o3;
        reinterpret_cast<ushort4*>(dst)[i] = pk;
    }
}

// bc[l][j] = b_ih[l][j] + (j<512 ? b_hh[l][j] : 0)   (fold r,z hidden-bias into gi)
__global__ void bias_combine(const float* __restrict__ bih, const float* __restrict__ bhh,
                             float* __restrict__ bc, int n) {
    int i = blockIdx.x * blockDim.x + threadIdx.x;
    if (i < n) {
        int j = i % NG;
        bc[i] = bih[i] + (j < 512 ? bhh[i] : 0.f);
    }
}

// ---------------- input GEMM: C[m,n] = (bf16) sum_k A[m,k]*W[n,k] + bias[n] ----------
// A: (M, K) row-major (fp32 if F32IN else bf16); W: (768, K) bf16 row-major.
// 128x128 tile, BK=32, 4 waves (2x2), each wave 64x64 = 4x4 MFMA tiles.
template<int KT, bool F32IN>
__global__ __launch_bounds__(256) void gi_gemm(const void* __restrict__ Av,
                                               const bf16* __restrict__ W,
                                               const float* __restrict__ bias,
                                               bf16* __restrict__ C) {
    constexpr int K = KT * 32;
    __shared__ bf16 sA[128 * 32];
    __shared__ bf16 sB[128 * 32];
    const int tid = threadIdx.x;
    const int wid = tid >> 6, l = tid & 63;
    const int lr = l & 15, lg = l >> 4;
    const int m0 = blockIdx.x * 128, n0 = blockIdx.y * 128;
    const int wm = (wid & 1) * 64, wn = (wid >> 1) * 64;
    const int srow = tid >> 2, skoff = (tid & 3) * 8;
    const bf16* pB = W + (size_t)(n0 + srow) * K + skoff;

    f32x4 acc[4][4] = {};
    for (int kt = 0; kt < KT; ++kt) {
        bf16x8 ta0, ta1;
        if (F32IN) {
            const float* pA = (const float*)Av + (size_t)(m0 + srow) * K + kt * 32 + skoff;
            float4 v0 = *(const float4*)pA;
            float4 v1 = *(const float4*)(pA + 4);
            ta0 = bf16x8{(bf16)v0.x,(bf16)v0.y,(bf16)v0.z,(bf16)v0.w,
                         (bf16)v1.x,(bf16)v1.y,(bf16)v1.z,(bf16)v1.w};
            const float* pA1 = pA + (size_t)64 * K;
            float4 u0 = *(const float4*)pA1;
            float4 u1 = *(const float4*)(pA1 + 4);
            ta1 = bf16x8{(bf16)u0.x,(bf16)u0.y,(bf16)u0.z,(bf16)u0.w,
                         (bf16)u1.x,(bf16)u1.y,(bf16)u1.z,(bf16)u1.w};
        } else {
            const bf16* pA = (const bf16*)Av + (size_t)(m0 + srow) * K + kt * 32 + skoff;
            ta0 = *(const bf16x8*)pA;
            ta1 = *(const bf16x8*)(pA + (size_t)64 * K);
        }
        bf16x8 tb0 = *(const bf16x8*)(pB + kt * 32);
        bf16x8 tb1 = *(const bf16x8*)(pB + (size_t)64 * K + kt * 32);
        __syncthreads();
        *(bf16x8*)((char*)sA + tid * 16)        = ta0;
        *(bf16x8*)((char*)sA + 4096 + tid * 16) = ta1;
        *(bf16x8*)((char*)sB + tid * 16)        = tb0;
        *(bf16x8*)((char*)sB + 4096 + tid * 16) = tb1;
        __syncthreads();
        bf16x8 av[4], bv[4];
#pragma unroll
        for (int i = 0; i < 4; ++i)
            av[i] = *(const bf16x8*)((char*)sA + (wm + i * 16 + lr) * 64 + lg * 16);
#pragma unroll
        for (int j = 0; j < 4; ++j)
            bv[j] = *(const bf16x8*)((char*)sB + (wn + j * 16 + lr) * 64 + lg * 16);
#pragma unroll
        for (int i = 0; i < 4; ++i)
#pragma unroll
            for (int j = 0; j < 4; ++j)
                acc[i][j] = __builtin_amdgcn_mfma_f32_16x16x32_bf16(av[i], bv[j], acc[i][j], 0, 0, 0);
    }
    // epilogue: per tile, C row = lg*4+q (M), col = lr (N)
#pragma unroll
    for (int j = 0; j < 4; ++j) {
        int col = n0 + wn + j * 16 + lr;
        float bj = bias[col];
#pragma unroll
        for (int i = 0; i < 4; ++i) {
            size_t mrow = (size_t)m0 + wm + i * 16 + lg * 4;
            bf16* cp = C + mrow * NG + col;
#pragma unroll
            for (int q = 0; q < 4; ++q)
                cp[(size_t)q * NG] = (bf16)(acc[i][j][q] + bj);
        }
    }
}

// ---------------- recurrent scan, W_hh resident in VGPRs ----------------
__device__ __forceinline__ float sigm(float x) {
    return __builtin_amdgcn_rcpf(1.f + __expf(-x));
}
__device__ __forceinline__ float tanh_f(float x) {
    return __builtin_amdgcn_rcpf(1.f + __expf(-2.f * x)) * 2.f - 1.f;
}

// 16 blocks x 512 threads (8 waves). Block owns batch rows [b0, b0+16).
// Wave w owns H-columns [32w, 32w+32) of all 3 gates:
//   48 B-fragments (bf16x8) = 192 VGPRs/lane -> whole W_hh (384 KB bf16) in CU registers.
// gi (bf16) is double-buffer prefetched into LDS via global_load_lds (zero VGPR cost).
// h: bf16 copy in LDS (stride 264), fp32 master in registers.
template<int LAST>
__global__ __launch_bounds__(512, 2) void gru_recur(
        const bf16* __restrict__ gi,       // (nt, NB, NG) bf16 chunk
        const bf16* __restrict__ Whh,
        const float* __restrict__ bhn_p,   // b_hh[l] + 512 (n-gate hidden bias)
        const float* __restrict__ hinit,
        float* __restrict__ hstate,
        bf16* __restrict__ ybf,            // bf16 out (if !LAST)
        float* __restrict__ yf,            // d_out fp32 (if LAST)
        int t0, int nt) {
    __shared__ bf16 hs[16][264];
    __shared__ unsigned short gib[2][16 * NG];   // 2 x 24576 B
    const int tid = threadIdx.x;
    const int w = tid >> 6, l = tid & 63;
    const int lr = l & 15, lg = l >> 4;
    const int b0 = blockIdx.x * 16;
    const int jw = w * 32;

    // W_hh B-fragments: B[k][n] = Whh[n][k], n = g*256 + jw + jt*16 + lr
    bf16x8 wf[3][2][8];
#pragma unroll
    for (int g = 0; g < 3; ++g)
#pragma unroll
        for (int jt = 0; jt < 2; ++jt) {
            const bf16* wp = Whh + (size_t)(g * 256 + jw + jt * 16 + lr) * NH + lg * 8;
#pragma unroll
            for (int kt = 0; kt < 8; ++kt)
                wf[g][jt][kt] = *(const bf16x8*)(wp + kt * 32);
        }

    float bhn[2];
#pragma unroll
    for (int jt = 0; jt < 2; ++jt)
        bhn[jt] = bhn_p[jw + jt * 16 + lr];

    // prefetch gi(t=0): block slice is contiguous 24576 B; 3 x 16B-wide loads/wave
    {
        const char* src = (const char*)gi + (size_t)b0 * (NG * 2);
#pragma unroll
        for (int i = 0; i < 3; ++i) {
            int off = (w * 3 + i) * 1024;
            __builtin_amdgcn_global_load_lds(
                (const __attribute__((address_space(1))) void*)(src + off + l * 16),
                (__attribute__((address_space(3))) void*)((char*)&gib[0][0] + off),
                16, 0, 0);
        }
    }

    float hreg[2][4];
#pragma unroll
    for (int jt = 0; jt < 2; ++jt)
#pragma unroll
        for (int q = 0; q < 4; ++q) {
            int row = lg * 4 + q, col = jw + jt * 16 + lr;
            float h = hinit[(size_t)(b0 + row) * NH + col];
            hreg[jt][q] = h;
            hs[row][col] = (bf16)h;
        }
    __syncthreads();   // drains vmcnt (gib[0] ready) + lgkm (hs ready)

    for (int t = 0; t < nt; ++t) {
        const int cur = t & 1;
        // gh = h @ Whh^T for this wave's 96 gate-columns
        f32x4 acc[3][2] = {};
#pragma unroll
        for (int kt = 0; kt < 8; ++kt) {
            bf16x8 a = *(const bf16x8*)((const char*)hs + lr * 528 + kt * 64 + lg * 16);
#pragma unroll
            for (int g = 0; g < 3; ++g)
#pragma unroll
                for (int jt = 0; jt < 2; ++jt)
                    acc[g][jt] = __builtin_amdgcn_mfma_f32_16x16x32_bf16(a, wf[g][jt][kt], acc[g][jt], 0, 0, 0);
        }
        __syncthreads();   // barrier-1: hs reads done (also: prefetch t complete)

        // issue prefetch for t+1 (lands by barrier-2's vmcnt drain)
        if (t + 1 < nt) {
            const char* src = (const char*)gi + ((size_t)(t + 1) * NB + b0) * (NG * 2);
#pragma unroll
            for (int i = 0; i < 3; ++i) {
                int off = (w * 3 + i) * 1024;
                __builtin_amdgcn_global_load_lds(
                    (const __attribute__((address_space(1))) void*)(src + off + l * 16),
                    (__attribute__((address_space(3))) void*)((char*)&gib[cur ^ 1][0] + off),
                    16, 0, 0);
            }
        }

        const unsigned short* gb = &gib[cur][0];
#pragma unroll
        for (int jt = 0; jt < 2; ++jt)
#pragma unroll
            for (int q = 0; q < 4; ++q) {
                int row = lg * 4 + q, col = jw + jt * 16 + lr;
                const unsigned short* p = gb + row * NG + col;
                float ir  = bf2f(p[0]);
                float iz  = bf2f(p[256]);
                float inn = bf2f(p[512]);
                float r = sigm(ir + acc[0][jt][q]);          // b_hh_r folded into gi
                float z = sigm(iz + acc[1][jt][q]);          // b_hh_z folded into gi
                float n = tanh_f(inn + r * (acc[2][jt][q] + bhn[jt]));
                float h = hreg[jt][q];
                float hn = n + z * (h - n);
                hreg[jt][q] = hn;
                hs[row][col] = (bf16)hn;
                size_t oidx = ((size_t)(t0 + t) * NB + b0 + row) * NH + col;
                if (LAST) yf[oidx] = hn;
                else      ybf[oidx] = (bf16)hn;
            }
        __syncthreads();   // barrier-2: hs writes visible; gib[cur^1] landed
    }
    // persist h for next chunk
#pragma unroll
    for (int jt = 0; jt < 2; ++jt)
#pragma unroll
        for (int q = 0; q < 4; ++q) {
            int row = lg * 4 + q, col = jw + jt * 16 + lr;
            hstate[(size_t)(b0 + row) * NH + col] = hreg[jt][q];
        }
}

// ---------------- launcher ----------------
extern "C" void kernel_launch(void* const* d_in, const int* in_sizes, int n_in,
                              void* d_out, int out_size, void* d_ws, size_t ws_size,
                              hipStream_t stream) {
    const float* x    = (const float*)d_in[0];
    const float* h0   = (const float*)d_in[1];
    const float* wih0 = (const float*)d_in[2];
    const float* wihr = (const float*)d_in[3];
    const float* whh  = (const float*)d_in[4];
    const float* bih  = (const float*)d_in[5];
    const float* bhh  = (const float*)d_in[6];

    // fixed ws carve (bytes): total 4,802,560
    char* wsp = (char*)d_ws;
    bf16*  wbih0  = (bf16*)(wsp + 0);          // 768*128*2      = 196,608
    bf16*  wbihr  = (bf16*)(wsp + 196608);     // 5*768*256*2    = 1,966,080
    bf16*  wbhh   = (bf16*)(wsp + 2162688);    // 6*768*256*2    = 2,359,296
    float* bc     = (float*)(wsp + 4521984);   // 6*768*4        = 18,432
    float* hstate = (float*)(wsp + 4540416);   // 256*256*4      = 262,144
    bf16*  gi     = (bf16*)(wsp + 4802560);    // Tc*256*768*2 per chunk

    const size_t FIXED = 4802560;
    const size_t CHUNK1 = (size_t)NB * NG * 2; // 393,216 B per timestep (bf16)
    size_t avail = ws_size > FIXED ? ws_size - FIXED : 0;
    int Tc = T_SEQ;
    while (Tc > 1 && (size_t)Tc * CHUNK1 > avail) Tc >>= 1;
    if ((size_t)Tc * CHUNK1 > avail) return;   // ws hopelessly small (<5.2 MB)
    const int nc = T_SEQ / Tc;

    // one-time (per-call) weight/bias prep
    cvt_kernel<<<96,   256, 0, stream>>>(wih0, wbih0, 98304 / 4);
    cvt_kernel<<<960,  256, 0, stream>>>(wihr, wbihr, 983040 / 4);
    cvt_kernel<<<1152, 256, 0, stream>>>(whh,  wbhh,  1179648 / 4);
    bias_combine<<<18, 256, 0, stream>>>(bih, bhh, bc, NL * NG);

    // y ping-pong lives inside d_out: lower/upper 64 MB bf16 halves.
    // even layer -> upper half; last-layer fp32 writes never clobber unread y4
    // rows: (c+1)*Tc*262144 <= 67108864 + (c+1)*Tc*131072 for (c+1)*Tc <= 512.
    bf16* yhalf0 = (bf16*)d_out;
    bf16* yhalf1 = (bf16*)((char*)d_out + 67108864);

    const void* gin = x;
    bool ginF32 = true;
    for (int lyr = 0; lyr < NL; ++lyr) {
        const bf16* wih = (lyr == 0) ? wbih0 : wbihr + (size_t)(lyr - 1) * NG * NH;
        bf16* yout = (lyr % 2 == 0) ? yhalf1 : yhalf0;
        const bf16* whh_l = wbhh + (size_t)lyr * NG * NH;
        const float* bhn_l = bhh + (size_t)lyr * NG + 512;

        for (int c = 0; c < nc; ++c) {
            dim3 gg(Tc * 2, NG / 128);   // (Tc*256/128, 6)
            if (ginF32) {
                const void* Ap = (const void*)((const float*)gin + (size_t)c * Tc * NB * IND);
                gi_gemm<4, true><<<gg, 256, 0, stream>>>(Ap, wih, bc + lyr * NG, gi);
            } else {
                const void* Ap = (const void*)((const bf16*)gin + (size_t)c * Tc * NB * NH);
                gi_gemm<8, false><<<gg, 256, 0, stream>>>(Ap, wih, bc + lyr * NG, gi);
            }
            const float* hin = (c == 0) ? h0 + (size_t)lyr * NB * NH : hstate;
            if (lyr == NL - 1)
                gru_recur<1><<<16, 512, 0, stream>>>(gi, whh_l, bhn_l, hin, hstate,
                                                     (bf16*)nullptr, (float*)d_out,
                                                     c * Tc, Tc);
            else
                gru_recur<0><<<16, 512, 0, stream>>>(gi, whh_l, bhn_l, hin, hstate,
                                                     yout, (float*)nullptr,
                                                     c * Tc, Tc);
        }
        gin = yout;
        ginF32 = false;
    }
}